// Round 10
// baseline (3634.657 us; speedup 1.0000x reference)
//
#include <hip/hip_runtime.h>
#include <hip/hip_bf16.h>
#include <math.h>

#define LSEQ 16384
#define NC 128          // chunks per direction (Q=128)

using short8  = __attribute__((ext_vector_type(8))) short;
using floatx4 = __attribute__((ext_vector_type(4))) float;

__device__ __forceinline__ float bf2f(ushort u){ union{unsigned u; float f;} x; x.u = ((unsigned)u)<<16; return x.f; }
__device__ __forceinline__ ushort f2bf(float f){ union{float f; unsigned u;} x; x.f=f; unsigned u=x.u; return (ushort)((u + 0x7FFFu + ((u>>16)&1u)) >> 16); }
__device__ __forceinline__ float geluf(float x){ return 0.5f*x*(1.f+erff(x*0.70710678118654752f)); }
__device__ __forceinline__ float siluf(float x){ return x/(1.f+__expf(-x)); }
__device__ __forceinline__ float softplusf(float x){ return x>20.f ? x : log1pf(__expf(x)); }

__device__ __forceinline__ float blockSum256(float v, float* red){
  int t = threadIdx.x;
  red[t]=v; __syncthreads();
  #pragma unroll
  for (int s=128;s>0;s>>=1){ if (t<s) red[t]+=red[t+s]; __syncthreads(); }
  float r = red[0]; __syncthreads();
  return r;
}

__device__ const int ORD[6][3] = {{0,1,2},{0,2,1},{1,0,2},{1,2,0},{2,0,1},{2,1,0}};

// sort phase 1: zero rank buffer
__global__ __launch_bounds__(256) void zrank_k(int* __restrict__ rank){
  rank[blockIdx.x*256 + threadIdx.x] = 0;
}

// sort phase 2: partial rank counting; grid (16, 6, 8): 1024 i's per block, j-slice of 2048
__global__ __launch_bounds__(256) void sortp_k(const int* __restrict__ coords, int* __restrict__ rank){
  __shared__ unsigned long long sk[256];
  int d = blockIdx.y; int tid = threadIdx.x;
  int a0=ORD[d][0], a1=ORD[d][1], a2=ORD[d][2];
  int ibase = blockIdx.x*1024;
  int jbase = blockIdx.z*2048;
  unsigned long long mykey[4]; int rk[4] = {0,0,0,0};
  #pragma unroll
  for (int r=0;r<4;++r){
    int i = ibase + r*256 + tid;
    unsigned k3 = ((unsigned)coords[i*4+a0]<<14) | ((unsigned)coords[i*4+a1]<<7) | (unsigned)coords[i*4+a2];
    mykey[r] = (((unsigned long long)k3)<<14) | (unsigned)i;
  }
  for (int j0=jbase; j0<jbase+2048; j0+=256){
    int j = j0 + tid;
    unsigned j3 = ((unsigned)coords[j*4+a0]<<14) | ((unsigned)coords[j*4+a1]<<7) | (unsigned)coords[j*4+a2];
    sk[tid] = (((unsigned long long)j3)<<14) | (unsigned)j;
    __syncthreads();
    #pragma unroll 8
    for (int jj=0; jj<256; ++jj){
      unsigned long long kj = sk[jj];
      #pragma unroll
      for (int r=0;r<4;++r) rk[r] += (kj < mykey[r]) ? 1 : 0;
    }
    __syncthreads();
  }
  #pragma unroll
  for (int r=0;r<4;++r)
    atomicAdd(&rank[d*LSEQ + ibase + r*256 + tid], rk[r]);
}

// sort phase 3: build perm/inv from final ranks
__global__ __launch_bounds__(256) void sfin_k(const int* __restrict__ rank, int* __restrict__ perm, int* __restrict__ inv){
  int g = blockIdx.x*256 + threadIdx.x;
  int d = g >> 14, i = g & 16383;
  int r = rank[g];
  perm[d*LSEQ + r] = i;
  inv[g] = r;
}

__global__ __launch_bounds__(256) void concat_k(const float* __restrict__ vr, const float* __restrict__ vi, float* __restrict__ xcat){
  int idx = blockIdx.x*256 + threadIdx.x; // L*128
  int i = idx >> 7, c = idx & 127;
  xcat[idx] = (c<64) ? vr[(i<<6)+c] : vi[(i<<6)+c-64];
}

// LDS-tiled transpose: out[n*K+k] = bf16(in[k*N+n]); grid ((N+31)/32,(K+31)/32), 256 threads
__global__ __launch_bounds__(256) void tr_k(const float* __restrict__ in, ushort* __restrict__ out, int K, int N){
  __shared__ float tile[32][33];
  int tx = threadIdx.x & 31, ty = threadIdx.x >> 5;
  int k0 = blockIdx.y*32, n0 = blockIdx.x*32;
  #pragma unroll
  for (int q=0;q<4;++q){
    int k = k0 + ty + q*8, n = n0 + tx;
    if (k < K && n < N) tile[ty+q*8][tx] = in[(size_t)k*N + n];
  }
  __syncthreads();
  #pragma unroll
  for (int q=0;q<4;++q){
    int n = n0 + ty + q*8, k = k0 + tx;
    if (n < N && k < K) out[(size_t)n*K + k] = f2bf(tile[tx][ty+q*8]);
  }
}

// Prologue GEMM (small): C[M,N] = A[M,K] * Bt^T + bias, fp32 A, fp32 out
__global__ __launch_bounds__(256) void gemm0_k(
  const float* __restrict__ A, int lda, const ushort* __restrict__ Bt,
  int N, int K, float* __restrict__ of, const float* __restrict__ bias)
{
  __shared__ __align__(16) ushort As[64*32];
  __shared__ __align__(16) ushort Bs[64*32];
  int tid = threadIdx.x;
  int n0 = blockIdx.x*64, m0 = blockIdx.y*64;
  int w = tid>>6, lane = tid&63;
  int wm = (w>>1)*32, wn = (w&1)*32;
  int sr = tid>>2, skk = (tid&3)*8;
  floatx4 acc[2][2] = {};
  for (int k0=0; k0<K; k0+=32){
    float4 v0 = *(const float4*)(A + (size_t)(m0+sr)*lda + k0 + skk);
    float4 v1 = *(const float4*)(A + (size_t)(m0+sr)*lda + k0 + skk + 4);
    ushort o[8] = {f2bf(v0.x),f2bf(v0.y),f2bf(v0.z),f2bf(v0.w),f2bf(v1.x),f2bf(v1.y),f2bf(v1.z),f2bf(v1.w)};
    *(uint4*)(&As[sr*32+skk]) = *(uint4*)o;
    uint4 bv = make_uint4(0u,0u,0u,0u);
    if (n0+sr < N) bv = *(const uint4*)(Bt + (size_t)(n0+sr)*K + k0 + skk);
    *(uint4*)(&Bs[sr*32+skk]) = bv;
    __syncthreads();
    int kq = lane>>4, l16 = lane&15;
    short8 bf0 = *(const short8*)(&Bs[(wn      + l16)*32 + kq*8]);
    short8 bf1 = *(const short8*)(&Bs[(wn + 16 + l16)*32 + kq*8]);
    #pragma unroll
    for (int ti=0; ti<2; ++ti){
      short8 af = *(const short8*)(&As[(wm + ti*16 + l16)*32 + kq*8]);
      acc[ti][0] = __builtin_amdgcn_mfma_f32_16x16x32_bf16(af, bf0, acc[ti][0], 0,0,0);
      acc[ti][1] = __builtin_amdgcn_mfma_f32_16x16x32_bf16(af, bf1, acc[ti][1], 0,0,0);
    }
    __syncthreads();
  }
  int l16 = lane&15, lq = lane>>4;
  #pragma unroll
  for (int ti=0; ti<2; ++ti)
  #pragma unroll
  for (int tj=0; tj<2; ++tj)
  #pragma unroll
  for (int r=0; r<4; ++r){
    int row = m0 + wm + ti*16 + lq*4 + r;
    int col = n0 + wn + tj*16 + l16;
    if (col >= N) continue;
    of[(size_t)row*N + col] = acc[ti][tj][r] + bias[col];
  }
}

// gemm1: LDS-staged LN'd A (once); B staged in 64x128 chunks w/ register prefetch (16 MFMAs per barrier-pair).
// cols 0..639 -> xbc bf16 (pre-conv), 640..647 -> softplus dt (fp32)
__global__ __launch_bounds__(256) void gemm1_k(
  const float* __restrict__ xs,
  const float* __restrict__ lnw, const float* __restrict__ lnb,
  const ushort* __restrict__ Wt,
  ushort* __restrict__ xbc, float* __restrict__ odt, const float* __restrict__ dtb)
{
  __shared__ __align__(16) ushort As[64*264];
  __shared__ __align__(16) ushort Bs[64*136];
  int tid = threadIdx.x;
  int m0 = blockIdx.x*64;
  int w = tid>>6, lane = tid&63;
  int wm = (w>>1)*32, wn = (w&1)*32;
  int sr = tid>>2, skk = (tid&3)*8;
  int sb = (tid&3)*32;
  int l16 = lane&15, kq = lane>>4;
  // stage A-row + fused LN stats (4 threads per row, shuffle-reduce over lane&3)
  {
    float va[8][8];
    float s = 0.f, s2 = 0.f;
    const float* rowp = xs + (size_t)(m0+sr)*256;
    #pragma unroll
    for (int ki=0;ki<8;++ki){
      float4 v0 = *(const float4*)(rowp + ki*32 + skk);
      float4 v1 = *(const float4*)(rowp + ki*32 + skk + 4);
      va[ki][0]=v0.x; va[ki][1]=v0.y; va[ki][2]=v0.z; va[ki][3]=v0.w;
      va[ki][4]=v1.x; va[ki][5]=v1.y; va[ki][6]=v1.z; va[ki][7]=v1.w;
      #pragma unroll
      for (int j=0;j<8;++j){ s += va[ki][j]; s2 += va[ki][j]*va[ki][j]; }
    }
    s  += __shfl_xor(s,1,64);  s  += __shfl_xor(s,2,64);
    s2 += __shfl_xor(s2,1,64); s2 += __shfl_xor(s2,2,64);
    float mu = s*(1.f/256.f);
    float var = s2*(1.f/256.f) - mu*mu;
    float rs = rsqrtf(fmaxf(var,0.f)+1e-5f);
    #pragma unroll
    for (int ki=0;ki<8;++ki){
      ushort o[8];
      #pragma unroll
      for (int j=0;j<8;++j) o[j] = f2bf((va[ki][j]-mu)*rs*lnw[ki*32+skk+j] + lnb[ki*32+skk+j]);
      *(uint4*)(&As[sr*264 + ki*32 + skk]) = *(uint4*)o;
    }
  }
  for (int nt=0; nt<11; ++nt){
    floatx4 acc[2][2] = {};
    #pragma unroll
    for (int kb=0; kb<2; ++kb){
      int nr = 512 + nt*64 + sr;
      uint4 bv[4] = {};
      if (nr < 1160){
        #pragma unroll
        for (int j=0;j<4;++j) bv[j] = *(const uint4*)(Wt + (size_t)nr*256 + kb*128 + sb + j*8);
      }
      __syncthreads();   // protect previous chunk reads (also covers initial A-stage)
      #pragma unroll
      for (int j=0;j<4;++j) *(uint4*)(&Bs[sr*136 + sb + j*8]) = bv[j];
      __syncthreads();
      #pragma unroll
      for (int kc=0;kc<4;++kc){
        #pragma unroll
        for (int tj=0;tj<2;++tj){
          short8 bfr = *(const short8*)(&Bs[(wn + tj*16 + l16)*136 + kc*32 + kq*8]);
          #pragma unroll
          for (int mt=0;mt<2;++mt){
            short8 af = *(const short8*)(&As[(wm + mt*16 + l16)*264 + kb*128 + kc*32 + kq*8]);
            acc[mt][tj] = __builtin_amdgcn_mfma_f32_16x16x32_bf16(af, bfr, acc[mt][tj], 0,0,0);
          }
        }
      }
    }
    #pragma unroll
    for (int mt=0; mt<2; ++mt)
    #pragma unroll
    for (int tj=0; tj<2; ++tj)
    #pragma unroll
    for (int r=0; r<4; ++r){
      int row = m0 + wm + mt*16 + kq*4 + r;
      int col = nt*64 + wn + tj*16 + l16;
      float v = acc[mt][tj][r];
      if (col < 640) xbc[(size_t)row*640 + col] = f2bf(v);
      else if (col < 648) odt[(size_t)row*8 + (col-640)] = softplusf(v + dtb[col-640]);
    }
  }
}

// zgate: LDS-staged LN'd A; B in 64x128 prefetched chunks; g = y*silu(z); in-place; rrg via shuffle+tiny LDS
__global__ __launch_bounds__(256) void zgate_k(
  const float* __restrict__ xs,
  const float* __restrict__ lnw, const float* __restrict__ lnb,
  const ushort* __restrict__ Wzt, ushort* __restrict__ xbc,
  const float* __restrict__ rmsw, float* __restrict__ rrg)
{
  __shared__ __align__(16) ushort As[64*264];
  __shared__ __align__(16) ushort Bs[64*136];
  __shared__ float gsum2[128];
  int tid = threadIdx.x;
  int m0 = blockIdx.x*64;
  int w = tid>>6, lane = tid&63;
  int wm = (w>>1)*32, wn = (w&1)*32;
  int sr = tid>>2, skk = (tid&3)*8;
  int sb = (tid&3)*32;
  int l16 = lane&15, kq = lane>>4;
  {
    float va[8][8];
    float s = 0.f, s2 = 0.f;
    const float* rowp = xs + (size_t)(m0+sr)*256;
    #pragma unroll
    for (int ki=0;ki<8;++ki){
      float4 v0 = *(const float4*)(rowp + ki*32 + skk);
      float4 v1 = *(const float4*)(rowp + ki*32 + skk + 4);
      va[ki][0]=v0.x; va[ki][1]=v0.y; va[ki][2]=v0.z; va[ki][3]=v0.w;
      va[ki][4]=v1.x; va[ki][5]=v1.y; va[ki][6]=v1.z; va[ki][7]=v1.w;
      #pragma unroll
      for (int j=0;j<8;++j){ s += va[ki][j]; s2 += va[ki][j]*va[ki][j]; }
    }
    s  += __shfl_xor(s,1,64);  s  += __shfl_xor(s,2,64);
    s2 += __shfl_xor(s2,1,64); s2 += __shfl_xor(s2,2,64);
    float mu = s*(1.f/256.f);
    float var = s2*(1.f/256.f) - mu*mu;
    float rs = rsqrtf(fmaxf(var,0.f)+1e-5f);
    #pragma unroll
    for (int ki=0;ki<8;++ki){
      ushort o[8];
      #pragma unroll
      for (int j=0;j<8;++j) o[j] = f2bf((va[ki][j]-mu)*rs*lnw[ki*32+skk+j] + lnb[ki*32+skk+j]);
      *(uint4*)(&As[sr*264 + ki*32 + skk]) = *(uint4*)o;
    }
  }
  float racc[2][4] = {};
  for (int nt=0; nt<8; ++nt){
    floatx4 acc[2][2] = {};
    #pragma unroll
    for (int kb=0; kb<2; ++kb){
      int nr = nt*64 + sr;
      uint4 bv[4];
      #pragma unroll
      for (int j=0;j<4;++j) bv[j] = *(const uint4*)(Wzt + (size_t)nr*256 + kb*128 + sb + j*8);
      __syncthreads();
      #pragma unroll
      for (int j=0;j<4;++j) *(uint4*)(&Bs[sr*136 + sb + j*8]) = bv[j];
      __syncthreads();
      #pragma unroll
      for (int kc=0;kc<4;++kc){
        #pragma unroll
        for (int tj=0;tj<2;++tj){
          short8 bfr = *(const short8*)(&Bs[(wn + tj*16 + l16)*136 + kc*32 + kq*8]);
          #pragma unroll
          for (int mt=0;mt<2;++mt){
            short8 af = *(const short8*)(&As[(wm + mt*16 + l16)*264 + kb*128 + kc*32 + kq*8]);
            acc[mt][tj] = __builtin_amdgcn_mfma_f32_16x16x32_bf16(af, bfr, acc[mt][tj], 0,0,0);
          }
        }
      }
    }
    #pragma unroll
    for (int mt=0; mt<2; ++mt)
    #pragma unroll
    for (int tj=0; tj<2; ++tj)
    #pragma unroll
    for (int r=0; r<4; ++r){
      int row = m0 + wm + mt*16 + kq*4 + r;
      int col = nt*64 + wn + tj*16 + l16;
      float z = acc[mt][tj][r];
      float y = bf2f(xbc[(size_t)row*640 + col]);
      float g = y * siluf(z);
      racc[mt][r] += g*g;
      xbc[(size_t)row*640 + col] = f2bf(g * rmsw[col]);
    }
  }
  #pragma unroll
  for (int mt=0; mt<2; ++mt)
  #pragma unroll
  for (int r=0; r<4; ++r){
    float v = racc[mt][r];
    v += __shfl_xor(v,1,64); v += __shfl_xor(v,2,64);
    v += __shfl_xor(v,4,64); v += __shfl_xor(v,8,64);
    if (l16 == 0) gsum2[(wm + mt*16 + kq*4 + r)*2 + (w&1)] = v;
  }
  __syncthreads();
  if (tid < 64)
    rrg[m0+tid] = rsqrtf((gsum2[tid*2] + gsum2[tid*2+1])*(1.f/512.f) + 1e-5f);
}

// gemmNS: N=256 (4 n-tiles, persistent acc), K=KC*256; A bf16 (lda) LDS-staged per kb; B 64x128 prefetched chunks.
// EPI: 2 = of += acc*rrow[row]; 3 = of = gelu(acc + bias)
template<int KC, int EPI>
__global__ __launch_bounds__(256) void gemmNS_k(
  const ushort* __restrict__ A, int lda, const ushort* __restrict__ Bt,
  float* __restrict__ of, const float* __restrict__ bias, const float* __restrict__ rrow)
{
  __shared__ __align__(16) ushort As[64*264];
  __shared__ __align__(16) ushort Bs[64*136];
  const int K = KC*256;
  int tid = threadIdx.x;
  int m0 = blockIdx.x*64;
  int w = tid>>6, lane = tid&63;
  int wm = (w>>1)*32, wn = (w&1)*32;
  int sr = tid>>2, skk = (tid&3)*8;
  int sb = (tid&3)*32;
  int l16 = lane&15, kq = lane>>4;
  floatx4 acc[4][2][2] = {};
  for (int kb=0; kb<KC; ++kb){
    uint4 av[8];
    #pragma unroll
    for (int ki=0;ki<8;++ki)
      av[ki] = *(const uint4*)(A + (size_t)(m0+sr)*lda + kb*256 + ki*32 + skk);
    __syncthreads();
    #pragma unroll
    for (int ki=0;ki<8;++ki)
      *(uint4*)(&As[sr*264 + ki*32 + skk]) = av[ki];
    __syncthreads();
    for (int nt=0; nt<4; ++nt){
      #pragma unroll
      for (int kh=0; kh<2; ++kh){
        uint4 bv[4];
        #pragma unroll
        for (int j=0;j<4;++j)
          bv[j] = *(const uint4*)(Bt + (size_t)(nt*64+sr)*K + kb*256 + kh*128 + sb + j*8);
        __syncthreads();
        #pragma unroll
        for (int j=0;j<4;++j) *(uint4*)(&Bs[sr*136 + sb + j*8]) = bv[j];
        __syncthreads();
        #pragma unroll
        for (int kc=0;kc<4;++kc){
          #pragma unroll
          for (int tj=0;tj<2;++tj){
            short8 bfr = *(const short8*)(&Bs[(wn + tj*16 + l16)*136 + kc*32 + kq*8]);
            #pragma unroll
            for (int mt=0;mt<2;++mt){
              short8 af = *(const short8*)(&As[(wm + mt*16 + l16)*264 + kh*128 + kc*32 + kq*8]);
              acc[nt][mt][tj] = __builtin_amdgcn_mfma_f32_16x16x32_bf16(af, bfr, acc[nt][mt][tj], 0,0,0);
            }
          }
        }
      }
    }
    __syncthreads();   // protect As before next kb overwrite
  }
  #pragma unroll
  for (int nt=0; nt<4; ++nt)
  #pragma unroll
  for (int mt=0; mt<2; ++mt)
  #pragma unroll
  for (int tj=0; tj<2; ++tj)
  #pragma unroll
  for (int r=0; r<4; ++r){
    int row = m0 + wm + mt*16 + kq*4 + r;
    int col = nt*64 + wn + tj*16 + l16;
    float v = acc[nt][mt][tj][r];
    if (EPI==2) of[(size_t)row*256 + col] += v * rrow[row];
    else        of[(size_t)row*256 + col] = geluf(v + bias[col]);
  }
}

__global__ __launch_bounds__(256) void ln_gelu_k(const float* __restrict__ in, float* __restrict__ out,
    const float* __restrict__ w, const float* __restrict__ b){
  __shared__ float red[256];
  int t = threadIdx.x; size_t base = (size_t)blockIdx.x*256;
  float v = in[base+t];
  float mu = blockSum256(v, red) * (1.f/256.f);
  float dv = v - mu;
  float var = blockSum256(dv*dv, red) * (1.f/256.f);
  float rs = rsqrtf(var + 1e-5f);
  out[base+t] = geluf(dv*rs*w[t] + b[t]);
}

__global__ __launch_bounds__(256) void scatter_k(const float* __restrict__ h, const int* __restrict__ perm, float* __restrict__ xs){
  int blk = blockIdx.x;
  int t = threadIdx.x;
  int d = blk >> 14; int r = blk & 16383;
  int src = perm[d*LSEQ + r];
  xs[(size_t)blk*256 + t] = h[(size_t)src*256 + t];
}

// save 3-row raw lookback per chunk before the in-place conv overwrite; grid 6*NC
__global__ __launch_bounds__(256) void bnd_k(const ushort* __restrict__ xbc, ushort* __restrict__ bnd){
  int b = blockIdx.x;
  int d = b / NC, c = b % NC;
  size_t row0 = (size_t)d*LSEQ + (size_t)c*128;
  for (int idx = threadIdx.x; idx < 3*640; idx += 256){
    int j = idx/640;
    ushort v = (c==0) ? (ushort)0 : xbc[(row0 - 3 + j)*640 + (idx - j*640)];
    bnd[(size_t)b*3*640 + idx] = v;
  }
}

// in-place causal depthwise conv + silu over xbc
__global__ __launch_bounds__(256) void conv_k(ushort* __restrict__ xbc, const ushort* __restrict__ bnd,
    const float* __restrict__ convw, const float* __restrict__ convb){
  int b = blockIdx.x;  // d*NC + c
  int d = b / NC, c = b % NC;
  size_t row0 = (size_t)d*LSEQ + (size_t)c*128;
  int tid = threadIdx.x;
  for (int s0 = tid; s0 < 640; s0 += 256){
    float w0=convw[s0*4], w1=convw[s0*4+1], w2=convw[s0*4+2], w3=convw[s0*4+3];
    float cb=convb[s0];
    float h0=0.f,h1=0.f,h2=0.f;
    if (c != 0){
      const ushort* bp = bnd + (size_t)b*3*640;
      h0=bf2f(bp[s0]); h1=bf2f(bp[640+s0]); h2=bf2f(bp[1280+s0]);
    }
    ushort* p = xbc + row0*640 + s0;
    for (int r=0;r<128;++r){
      float cur = bf2f(*p);
      *p = f2bf(siluf(cb + w0*h0 + w1*h1 + w2*h2 + w3*cur));
      h0=h1; h1=h2; h2=cur;
      p += 640;
    }
  }
}

// SSD pass A (conv'd input): dS[p][n] = sum_s exp(Ah*(cs[127]-cs[s]))*dt_s * x_s[p] * B_s[n]
__global__ __launch_bounds__(256) void ssd_dstate_k(
  const ushort* __restrict__ xbc, const float* __restrict__ dtf, const float* __restrict__ alog,
  ushort* __restrict__ dsb, float* __restrict__ gam, int dh0)
{
  int c = blockIdx.x, dhg = blockIdx.y;
  int dh = dh0 + dhg;
  int d = dh >> 3, h = dh & 7;
  int tid = threadIdx.x;
  float Ah = -__expf(alog[h]);
  __shared__ __align__(16) ushort XT[64*136];
  __shared__ __align__(16) ushort BwT[64*136];
  __shared__ float sdt[128];
  __shared__ float scs[128];
  size_t row0 = (size_t)d*LSEQ + (size_t)c*128;
  if (tid < 128){
    float v = dtf[(row0+tid)*8 + h];
    sdt[tid] = v;
    float x = v;
    #pragma unroll
    for (int o=1;o<64;o<<=1){ float t = __shfl_up(x,(unsigned)o,64); if ((tid&63)>=o) x += t; }
    scs[tid] = x;
  }
  __syncthreads();
  if (tid>=64 && tid<128) scs[tid] += scs[63];
  __syncthreads();
  float csLast = scs[127];
  if (tid == 0) gam[(size_t)dh*NC + c] = __expf(Ah*csLast);
  for (int idx = tid; idx < 128*16; idx += 256){
    int s = idx >> 4, g = idx & 15;
    int ch = (g<8) ? h*64 + g*8 : 512 + (g-8)*8;
    uint4 v = *(const uint4*)(xbc + (row0+s)*640 + ch);
    ushort u[8]; *(uint4*)u = v;
    if (g < 8){
      int c0 = g*8;
      #pragma unroll
      for (int j=0;j<8;++j) XT[(c0+j)*136 + s] = u[j];
    } else {
      float wgt = __expf(Ah*(csLast - scs[s])) * sdt[s];
      int n0 = (g-8)*8;
      #pragma unroll
      for (int j=0;j<8;++j) BwT[(n0+j)*136 + s] = f2bf(bf2f(u[j])*wgt);
    }
  }
  __syncthreads();
  int w = tid>>6, lane = tid&63, l16 = lane&15, kq = lane>>4;
  floatx4 acc[4] = {};
  #pragma unroll
  for (int kw=0; kw<4; ++kw){
    short8 bfrag = *(const short8*)(&BwT[(16*w + l16)*136 + kw*32 + kq*8]);
    #pragma unroll
    for (int mt=0; mt<4; ++mt){
      short8 afrag = *(const short8*)(&XT[(mt*16 + l16)*136 + kw*32 + kq*8]);
      acc[mt] = __builtin_amdgcn_mfma_f32_16x16x32_bf16(afrag, bfrag, acc[mt], 0,0,0);
    }
  }
  size_t base = ((size_t)dhg*NC + c)*4096;
  int n = 16*w + l16;
  int kb = n>>5, nm = n&31;
  #pragma unroll
  for (int mt=0; mt<4; ++mt)
  #pragma unroll
  for (int r=0; r<4; ++r){
    int p = mt*16 + kq*4 + r;
    dsb[base + (size_t)kb*2048 + p*32 + nm] = f2bf(acc[mt][r]);
  }
}

// SSD pass B: grid (g, 2); each block scans half the state (2048 elems, 8/thread), 4-deep prefetch
__global__ __launch_bounds__(256) void ssd_scan_k(ushort* __restrict__ dsb, const float* __restrict__ gam, int dh0)
{
  int dhg = blockIdx.x, z = blockIdx.y;
  int tid = threadIdx.x;
  float S[8];
  #pragma unroll
  for (int j=0;j<8;++j) S[j]=0.f;
  ushort* base = dsb + (size_t)dhg*NC*4096 + (size_t)z*2048 + (size_t)(tid>>2)*32 + (size_t)(tid&3)*8;
  const float* g = gam + (size_t)(dh0+dhg)*NC;
  uint4 pf[4];
  #pragma unroll
  for (int j=0;j<4;++j) pf[j] = *(const uint4*)(base + (size_t)j*4096);
  for (int c=0;c<NC;++c){
    ushort cur[8];
    *(uint4*)cur = pf[c&3];
    if (c+4 < NC) pf[c&3] = *(const uint4*)(base + (size_t)(c+4)*4096);
    float gamma = g[c];
    ushort pfo[8];
    #pragma unroll
    for (int j=0;j<8;++j) pfo[j] = f2bf(S[j]);
    *(uint4*)(base + (size_t)c*4096) = *(uint4*)pfo;
    #pragma unroll
    for (int j=0;j<8;++j) S[j] = gamma*S[j] + bf2f(cur[j]);
  }
}

// SSD pass C (conv'd input): Y = a_t*(C @ Sin) + (Lmask o (C@B^T)) @ X + D*x ; y in-place into x-slice
__global__ __launch_bounds__(256) void ssd_out_k(
  ushort* __restrict__ xbc, const ushort* __restrict__ dsb,
  const float* __restrict__ dtf, const float* __restrict__ alog, const float* __restrict__ dskip, int dh0)
{
  int c = blockIdx.x, dhg = blockIdx.y;
  int dh = dh0 + dhg;
  int d = dh>>3, h = dh&7;
  int tid = threadIdx.x;
  float Ah = -__expf(alog[h]);
  float Dv = dskip[h];
  __shared__ __align__(16) ushort Cs[2][128][32];
  __shared__ __align__(16) ushort Bs2[2][128][32];
  __shared__ __align__(16) ushort XT[64*136];
  __shared__ __align__(16) ushort Pl[4][32*32];
  __shared__ float sdt[128];
  __shared__ float scs[128];
  size_t row0 = (size_t)d*LSEQ + (size_t)c*128;
  if (tid < 128){
    float v = dtf[(row0+tid)*8 + h];
    sdt[tid] = v;
    float x = v;
    #pragma unroll
    for (int o=1;o<64;o<<=1){ float t = __shfl_up(x,(unsigned)o,64); if ((tid&63)>=o) x += t; }
    scs[tid] = x;
  }
  __syncthreads();
  if (tid>=64 && tid<128) scs[tid] += scs[63];
  __syncthreads();
  for (int idx = tid; idx < 128*24; idx += 256){
    int s = idx/24, g = idx - s*24;
    int ch = (g<8) ? h*64 + g*8 : 512 + (g-8)*8;
    uint4 v = *(const uint4*)(xbc + (row0+s)*640 + ch);
    ushort u[8]; *(uint4*)u = v;
    if (g < 8){
      int c0 = g*8;
      #pragma unroll
      for (int j=0;j<8;++j) XT[(c0+j)*136 + s] = u[j];
    } else if (g < 16){
      int n0 = (g-8)*8;
      #pragma unroll
      for (int j=0;j<8;++j) Bs2[(n0+j)>>5][s][(n0+j)&31] = u[j];
    } else {
      int n0 = (g-16)*8;
      #pragma unroll
      for (int j=0;j<8;++j) Cs[(n0+j)>>5][s][(n0+j)&31] = u[j];
    }
  }
  int w = tid>>6, lane = tid&63, l16 = lane&15, kq = lane>>4;
  size_t pbase = ((size_t)dhg*NC + c)*4096;
  short8 sinf[4][2];
  #pragma unroll
  for (int nt=0; nt<4; ++nt)
  #pragma unroll
  for (int kb=0; kb<2; ++kb)
    sinf[nt][kb] = *(const short8*)(dsb + pbase + (size_t)kb*2048 + (nt*16+l16)*32 + kq*8);
  __syncthreads();
  short8 cfr[2][2];
  #pragma unroll
  for (int mt=0; mt<2; ++mt)
  #pragma unroll
  for (int kb=0; kb<2; ++kb)
    cfr[mt][kb] = *(const short8*)(&Cs[kb][w*32 + mt*16 + l16][kq*8]);
  floatx4 Y[2][4] = {};
  #pragma unroll
  for (int mt=0; mt<2; ++mt)
  #pragma unroll
  for (int nt=0; nt<4; ++nt)
  #pragma unroll
  for (int kb=0; kb<2; ++kb)
    Y[mt][nt] = __builtin_amdgcn_mfma_f32_16x16x32_bf16(cfr[mt][kb], sinf[nt][kb], Y[mt][nt], 0,0,0);
  #pragma unroll
  for (int mt=0; mt<2; ++mt){
    float ar[4];
    #pragma unroll
    for (int r=0;r<4;++r) ar[r] = __expf(Ah*scs[w*32 + mt*16 + kq*4 + r]);
    #pragma unroll
    for (int nt=0; nt<4; ++nt)
    #pragma unroll
    for (int r=0;r<4;++r) Y[mt][nt][r] *= ar[r];
  }
  for (int st=0; st<=w; ++st){
    floatx4 P[2][2] = {};
    #pragma unroll
    for (int nt2=0; nt2<2; ++nt2)
    #pragma unroll
    for (int kb=0; kb<2; ++kb){
      short8 bfr = *(const short8*)(&Bs2[kb][st*32 + nt2*16 + l16][kq*8]);
      #pragma unroll
      for (int mt=0; mt<2; ++mt)
        P[mt][nt2] = __builtin_amdgcn_mfma_f32_16x16x32_bf16(cfr[mt][kb], bfr, P[mt][nt2], 0,0,0);
    }
    #pragma unroll
    for (int mt=0; mt<2; ++mt)
    #pragma unroll
    for (int nt2=0; nt2<2; ++nt2)
    #pragma unroll
    for (int r=0; r<4; ++r){
      int tl = w*32 + mt*16 + kq*4 + r;
      int sl = st*32 + nt2*16 + l16;
      float e = __expf(fminf(Ah*(scs[tl]-scs[sl]), 0.f)) * sdt[sl];
      float v = (sl <= tl) ? P[mt][nt2][r]*e : 0.f;
      Pl[w][(mt*16 + kq*4 + r)*32 + nt2*16 + l16] = f2bf(v);
    }
    #pragma unroll
    for (int mt=0; mt<2; ++mt){
      short8 afr = *(const short8*)(&Pl[w][(mt*16 + l16)*32 + kq*8]);
      #pragma unroll
      for (int nt=0; nt<4; ++nt){
        short8 xfr = *(const short8*)(&XT[(nt*16 + l16)*136 + st*32 + kq*8]);
        Y[mt][nt] = __builtin_amdgcn_mfma_f32_16x16x32_bf16(afr, xfr, Y[mt][nt], 0,0,0);
      }
    }
  }
  #pragma unroll
  for (int mt=0; mt<2; ++mt)
  #pragma unroll
  for (int nt=0; nt<4; ++nt)
  #pragma unroll
  for (int r=0; r<4; ++r){
    int tl = w*32 + mt*16 + kq*4 + r;
    int p  = nt*16 + l16;
    float xv = bf2f(XT[p*136 + tl]);
    float yv = Y[mt][nt][r] + Dv*xv;
    xbc[(row0 + tl)*640 + h*64 + p] = f2bf(yv);
  }
}

// Ultimate fallback: sequential scan with conv fused (raw xbc input)
__global__ __launch_bounds__(512) void scan_legacy_k(ushort* __restrict__ xbc, const float* __restrict__ dtf,
  const float* __restrict__ convw, const float* __restrict__ convb,
  const float* __restrict__ alog, const float* __restrict__ dskip)
{
  int d = blockIdx.x >> 3, h = blockIdx.x & 7;
  int tid = threadIdx.x, p = tid & 63, sg = tid >> 6;
  float Ah = -__expf(alog[h]);
  float Dv = dskip[h];
  __shared__ float raw[19][192];
  __shared__ float cw[192][4];
  __shared__ float cb[192];
  __shared__ float sxc[16][192];
  __shared__ float sdt[16];
  __shared__ float sy[16][8][64];
  for (int c = tid; c < 192; c += 512){
    int ch = (c<64) ? h*64+c : (c<128 ? 512+(c-64) : 576+(c-128));
    #pragma unroll
    for (int k=0;k<4;++k) cw[c][k] = convw[ch*4+k];
    cb[c] = convb[ch];
  }
  for (int idx = tid; idx < 3*192; idx += 512) raw[idx/192][idx%192] = 0.f;
  float st[8];
  #pragma unroll
  for (int j=0;j<8;++j) st[j]=0.f;
  size_t rowbase = (size_t)d*LSEQ;
  __syncthreads();
  for (int t0=0; t0<LSEQ; t0+=16){
    for (int idx = tid; idx < 16*192; idx += 512){
      int tt = idx/192, c = idx%192;
      int ch = (c<64) ? h*64+c : (c<128 ? 512+(c-64) : 576+(c-128));
      raw[3+tt][c] = bf2f(xbc[(rowbase + t0 + tt)*640 + ch]);
    }
    if (tid < 16) sdt[tid] = dtf[(rowbase + t0 + tid)*8 + h];
    __syncthreads();
    for (int idx = tid; idx < 16*192; idx += 512){
      int tt = idx/192, c = idx%192;
      float v = cb[c] + cw[c][0]*raw[tt][c] + cw[c][1]*raw[tt+1][c]
                      + cw[c][2]*raw[tt+2][c] + cw[c][3]*raw[tt+3][c];
      sxc[tt][c] = siluf(v);
    }
    __syncthreads();
    for (int tt=0; tt<16; ++tt){
      float dtv = sdt[tt];
      float dA = __expf(dtv*Ah);
      float xb = dtv * sxc[tt][p];
      float Bl[8], Cl[8];
      #pragma unroll
      for (int q=0;q<2;++q){
        *(floatx4*)&Bl[q*4] = *(const floatx4*)&sxc[tt][64  + sg*8 + q*4];
        *(floatx4*)&Cl[q*4] = *(const floatx4*)&sxc[tt][128 + sg*8 + q*4];
      }
      float part = 0.f;
      #pragma unroll
      for (int j=0;j<8;++j){ st[j] = st[j]*dA + xb*Bl[j]; part += st[j]*Cl[j]; }
      sy[tt][sg][p] = part;
    }
    __syncthreads();
    for (int idx = tid; idx < 16*64; idx += 512){
      int tt = idx>>6, pp = idx&63;
      float yv = sy[tt][0][pp]+sy[tt][1][pp]+sy[tt][2][pp]+sy[tt][3][pp]
               + sy[tt][4][pp]+sy[tt][5][pp]+sy[tt][6][pp]+sy[tt][7][pp] + Dv*sxc[tt][pp];
      xbc[(rowbase + t0 + tt)*640 + h*64 + pp] = f2bf(yv);
    }
    for (int idx = tid; idx < 3*192; idx += 512){
      int r = idx/192, c = idx%192;
      raw[r][c] = raw[16+r][c];
    }
    __syncthreads();
  }
}

// gather 6 dirs via inv, LayerNorm over 1536, write bf16 (GEMM A-operand)
__global__ __launch_bounds__(256) void fuse_ln_k(const float* __restrict__ xs, const int* __restrict__ inv,
    const float* __restrict__ w, const float* __restrict__ b, ushort* __restrict__ out){
  __shared__ float red[256];
  int i = blockIdx.x, t = threadIdx.x;
  float v[6];
  float s = 0.f;
  #pragma unroll
  for (int d=0; d<6; ++d){
    int r = inv[d*LSEQ + i];
    v[d] = xs[((size_t)d*LSEQ + r)*256 + t];
    s += v[d];
  }
  float mu = blockSum256(s, red) * (1.f/1536.f);
  float s2 = 0.f;
  #pragma unroll
  for (int d=0; d<6; ++d){ float dv = v[d]-mu; s2 += dv*dv; }
  float var = blockSum256(s2, red) * (1.f/1536.f);
  float rs = rsqrtf(var + 1e-5f);
  #pragma unroll
  for (int d=0; d<6; ++d){
    int c = d*256 + t;
    out[(size_t)i*1536 + c] = f2bf((v[d]-mu)*rs*w[c] + b[c]);
  }
}

__global__ void zero_k(float* p){ p[threadIdx.x] = 0.f; }

__global__ __launch_bounds__(256) void pool_k(const float* __restrict__ fused, float* __restrict__ pooled){
  int t = threadIdx.x;
  size_t r0 = (size_t)blockIdx.x*256;
  float s = 0.f;
  for (int r=0;r<256;++r) s += fused[(r0+r)*256 + t];
  atomicAdd(&pooled[t], s);
}

__global__ __launch_bounds__(256) void cls_k(const float* __restrict__ pooled,
  const float* __restrict__ lnw, const float* __restrict__ lnb,
  const float* __restrict__ w1, const float* __restrict__ b1,
  const float* __restrict__ w2, const float* __restrict__ b2,
  const float* __restrict__ w3, const float* __restrict__ b3, float* __restrict__ out)
{
  __shared__ float red[256];
  __shared__ float hcn[768]; __shared__ float h1[512]; __shared__ float h2[256];
  int t = threadIdx.x;
  float m = pooled[t] * (1.f/16384.f);
  float mu = blockSum256(m, red) * (1.f/256.f);
  float dv = m - mu;
  float var = blockSum256(dv*dv, red) * (1.f/256.f);
  float rs = rsqrtf(var + 1e-5f);
  #pragma unroll
  for (int rep=0; rep<3; ++rep){
    int c = rep*256 + t;
    hcn[c] = dv*rs*lnw[c] + lnb[c];
  }
  __syncthreads();
  for (int n=t; n<512; n+=256){
    float a = b1[n];
    for (int c=0;c<768;++c) a += hcn[c]*w1[c*512+n];
    h1[n] = geluf(a);
  }
  __syncthreads();
  {
    float a = b2[t];
    for (int c=0;c<512;++c) a += h1[c]*w2[c*256+t];
    h2[t] = geluf(a);
  }
  __syncthreads();
  if (t<11){
    float a = b3[t];
    for (int c=0;c<256;++c) a += h2[c]*w3[c*11+t];
    out[t] = a;
  }
}

extern "C" void kernel_launch(void* const* d_in, const int* in_sizes, int n_in,
                              void* d_out, int out_size, void* d_ws, size_t ws_size,
                              hipStream_t stream)
{
  const float* vec_real = (const float*)d_in[0];
  const float* vec_imag = (const float*)d_in[1];
  const int*   coords   = (const int*)d_in[2];
  const float* inp_w    = (const float*)d_in[3];
  const float* inp_b    = (const float*)d_in[4];
  const float* inp_ln_w = (const float*)d_in[5];
  const float* inp_ln_b = (const float*)d_in[6];
  const float* ln_w     = (const float*)d_in[7];
  const float* ln_b     = (const float*)d_in[8];
  const float* in_proj_w= (const float*)d_in[9];
  const float* conv_w   = (const float*)d_in[10];
  const float* conv_b   = (const float*)d_in[11];
  const float* dt_bias  = (const float*)d_in[12];
  const float* A_log    = (const float*)d_in[13];
  const float* Dskip    = (const float*)d_in[14];
  const float* rms_w    = (const float*)d_in[15];
  const float* out_proj_w=(const float*)d_in[16];
  const float* fus_ln_w = (const float*)d_in[17];
  const float* fus_ln_b = (const float*)d_in[18];
  const float* fus_w    = (const float*)d_in[19];
  const float* fus_b    = (const float*)d_in[20];
  const float* cls_ln_w = (const float*)d_in[21];
  const float* cls_ln_b = (const float*)d_in[22];
  const float* cls_w1   = (const float*)d_in[23];
  const float* cls_b1   = (const float*)d_in[24];
  const float* cls_w2   = (const float*)d_in[25];
  const float* cls_b2   = (const float*)d_in[26];
  const float* cls_w3   = (const float*)d_in[27];
  const float* cls_b3   = (const float*)d_in[28];
  (void)in_sizes; (void)n_in; (void)out_size;

  char* ws = (char*)d_ws;
  size_t off = 0;
  auto alloc = [&](size_t bytes)->char* { char* p = ws + off; off = (off + bytes + 255) & ~(size_t)255; return p; };
  int*    perm  = (int*)alloc((size_t)6*LSEQ*4);
  int*    inv   = (int*)alloc((size_t)6*LSEQ*4);
  float*  xs    = (float*)alloc((size_t)6*LSEQ*256*4);           // fp32 residual stream
  ushort* xbc   = (ushort*)alloc((size_t)6*LSEQ*640*2);          // raw xBC -> conv'd -> y -> gated g
  float*  dtfb  = (float*)alloc((size_t)6*LSEQ*8*4);
  float*  rrg   = (float*)alloc((size_t)6*LSEQ*4);               // also reused as sort rank buffer (int)
  ushort* wtr   = (ushort*)alloc((size_t)1536*256*2);
  float*  pooled= (float*)alloc(256*4);
  size_t base_off = off;
  if (base_off > ws_size) return;  // diagnostic guard

  // gam (48*NC fp32 = 24.6 KB) lives in the dead tail of wtr
  float* gam = (float*)((char*)wtr + 600*1024);
  int* rankb = (int*)rrg;   // sort scratch; rrg only live inside layer loop, sort runs before

  // adaptive SSD group size: largest g with bnd (2.95 MB) + dsb(g) fitting beyond base
  const size_t BND_SZ = (size_t)6*NC*3*640*2;
  size_t dsb_off = base_off + ((BND_SZ + 255) & ~(size_t)255);
  ushort* bndb = (ushort*)(ws + base_off);
  ushort* dsb  = (ushort*)(ws + dsb_off);
  long long avail2 = (long long)ws_size - (long long)dsb_off;
  int gsize = 0;
  const int cands[10] = {48,24,16,12,8,6,4,3,2,1};
  for (int ci=0; ci<10; ++ci){
    if ((long long)((size_t)cands[ci]*NC*4096*2 + 512) <= avail2){ gsize = cands[ci]; break; }
  }

  // prologue/epilogue temps aliased inside xbc (125.8 MB)
  float*  xcat = (float*)((char*)xbc + 0);
  float*  tmpF = (float*)((char*)xbc + (16u<<20));
  float*  hbuf = (float*)((char*)xbc + (48u<<20));
  ushort* multiB = (ushort*)((char*)xbc + 0);          // 48 MB bf16
  float*  fused  = (float*)((char*)xbc + (100u<<20));  // 16 MB

  dim3 b256(256);
  zrank_k<<<dim3(6*LSEQ/256),b256,0,stream>>>(rankb);
  sortp_k<<<dim3(16,6,8),b256,0,stream>>>(coords, rankb);
  sfin_k<<<dim3(6*LSEQ/256),b256,0,stream>>>(rankb, perm, inv);
  concat_k<<<dim3(LSEQ*128/256),b256,0,stream>>>(vec_real, vec_imag, xcat);
  tr_k<<<dim3(8,4),b256,0,stream>>>(inp_w, wtr, 128, 256);
  gemm0_k<<<dim3(4, LSEQ/64),b256,0,stream>>>(xcat, 128, wtr, 256, 128, tmpF, inp_b);
  ln_gelu_k<<<dim3(LSEQ),b256,0,stream>>>(tmpF, hbuf, inp_ln_w, inp_ln_b);
  scatter_k<<<dim3(6*LSEQ),b256,0,stream>>>(hbuf, perm, xs);

  for (int l=0;l<3;++l){
    const float* cwp = conv_w + (size_t)l*640*4;
    const float* cbp = conv_b + (size_t)l*640;
    const float* alp = A_log + l*8;
    const float* dkp = Dskip + l*8;
    tr_k<<<dim3(37,8),b256,0,stream>>>(in_proj_w + (size_t)l*256*1160, wtr, 256, 1160);
    gemm1_k<<<dim3(6*LSEQ/64),b256,0,stream>>>(xs, ln_w + l*256, ln_b + l*256,
        wtr, xbc, dtfb, dt_bias + l*8);
    if (gsize > 0){
      bnd_k<<<dim3(6*NC),b256,0,stream>>>(xbc, bndb);
      conv_k<<<dim3(6*NC),b256,0,stream>>>(xbc, bndb, cwp, cbp);
      for (int dh0=0; dh0<48; dh0+=gsize){
        ssd_dstate_k<<<dim3(NC,gsize),b256,0,stream>>>(xbc, dtfb, alp, dsb, gam, dh0);
        ssd_scan_k<<<dim3(gsize,2),b256,0,stream>>>(dsb, gam, dh0);
        ssd_out_k<<<dim3(NC,gsize),b256,0,stream>>>(xbc, dsb, dtfb, alp, dkp, dh0);
      }
    } else {
      scan_legacy_k<<<dim3(48),dim3(512),0,stream>>>(xbc, dtfb, cwp, cbp, alp, dkp);
    }
    zgate_k<<<dim3(6*LSEQ/64),b256,0,stream>>>(xs, ln_w + l*256, ln_b + l*256,
        wtr, xbc, rms_w + l*512, rrg);
    tr_k<<<dim3(8,16),b256,0,stream>>>(out_proj_w + (size_t)l*512*256, wtr, 512, 256);
    gemmNS_k<2,2><<<dim3(6*LSEQ/64),b256,0,stream>>>(xbc, 640, wtr, xs, nullptr, rrg);
  }

  fuse_ln_k<<<dim3(LSEQ),b256,0,stream>>>(xs, inv, fus_ln_w, fus_ln_b, multiB);
  tr_k<<<dim3(8,48),b256,0,stream>>>(fus_w, wtr, 1536, 256);
  gemmNS_k<6,3><<<dim3(LSEQ/64),b256,0,stream>>>(multiB, 1536, wtr, fused, fus_b, nullptr);
  zero_k<<<dim3(1),b256,0,stream>>>(pooled);
  pool_k<<<dim3(64),b256,0,stream>>>(fused, pooled);
  cls_k<<<dim3(1),b256,0,stream>>>(pooled, cls_ln_w, cls_ln_b, cls_w1, cls_b1, cls_w2, cls_b2, cls_w3, cls_b3, (float*)d_out);
}

// Round 11
// 2884.962 us; speedup vs baseline: 1.2599x; 1.2599x over previous
//
#include <hip/hip_runtime.h>
#include <hip/hip_bf16.h>
#include <math.h>

#define LSEQ 16384
#define NC 128          // chunks per direction (Q=128)

using short8  = __attribute__((ext_vector_type(8))) short;
using floatx4 = __attribute__((ext_vector_type(4))) float;

__device__ __forceinline__ float bf2f(ushort u){ union{unsigned u; float f;} x; x.u = ((unsigned)u)<<16; return x.f; }
__device__ __forceinline__ ushort f2bf(float f){ union{float f; unsigned u;} x; x.f=f; unsigned u=x.u; return (ushort)((u + 0x7FFFu + ((u>>16)&1u)) >> 16); }
__device__ __forceinline__ float geluf(float x){ return 0.5f*x*(1.f+erff(x*0.70710678118654752f)); }
__device__ __forceinline__ float siluf(float x){ return x/(1.f+__expf(-x)); }
__device__ __forceinline__ float softplusf(float x){ return x>20.f ? x : log1pf(__expf(x)); }

__device__ __forceinline__ float blockSum256(float v, float* red){
  int t = threadIdx.x;
  red[t]=v; __syncthreads();
  #pragma unroll
  for (int s=128;s>0;s>>=1){ if (t<s) red[t]+=red[t+s]; __syncthreads(); }
  float r = red[0]; __syncthreads();
  return r;
}

__device__ const int ORD[6][3] = {{0,1,2},{0,2,1},{1,0,2},{1,2,0},{2,0,1},{2,1,0}};

// sort phase 1: zero rank buffer
__global__ __launch_bounds__(256) void zrank_k(int* __restrict__ rank){
  rank[blockIdx.x*256 + threadIdx.x] = 0;
}

// sort phase 2: partial rank counting; grid (16, 6, 8): 1024 i's per block, j-slice of 2048
__global__ __launch_bounds__(256) void sortp_k(const int* __restrict__ coords, int* __restrict__ rank){
  __shared__ unsigned long long sk[256];
  int d = blockIdx.y; int tid = threadIdx.x;
  int a0=ORD[d][0], a1=ORD[d][1], a2=ORD[d][2];
  int ibase = blockIdx.x*1024;
  int jbase = blockIdx.z*2048;
  unsigned long long mykey[4]; int rk[4] = {0,0,0,0};
  #pragma unroll
  for (int r=0;r<4;++r){
    int i = ibase + r*256 + tid;
    unsigned k3 = ((unsigned)coords[i*4+a0]<<14) | ((unsigned)coords[i*4+a1]<<7) | (unsigned)coords[i*4+a2];
    mykey[r] = (((unsigned long long)k3)<<14) | (unsigned)i;
  }
  for (int j0=jbase; j0<jbase+2048; j0+=256){
    int j = j0 + tid;
    unsigned j3 = ((unsigned)coords[j*4+a0]<<14) | ((unsigned)coords[j*4+a1]<<7) | (unsigned)coords[j*4+a2];
    sk[tid] = (((unsigned long long)j3)<<14) | (unsigned)j;
    __syncthreads();
    #pragma unroll 8
    for (int jj=0; jj<256; ++jj){
      unsigned long long kj = sk[jj];
      #pragma unroll
      for (int r=0;r<4;++r) rk[r] += (kj < mykey[r]) ? 1 : 0;
    }
    __syncthreads();
  }
  #pragma unroll
  for (int r=0;r<4;++r)
    atomicAdd(&rank[d*LSEQ + ibase + r*256 + tid], rk[r]);
}

// sort phase 3: build perm/inv from final ranks
__global__ __launch_bounds__(256) void sfin_k(const int* __restrict__ rank, int* __restrict__ perm, int* __restrict__ inv){
  int g = blockIdx.x*256 + threadIdx.x;
  int d = g >> 14, i = g & 16383;
  int r = rank[g];
  perm[d*LSEQ + r] = i;
  inv[g] = r;
}

__global__ __launch_bounds__(256) void concat_k(const float* __restrict__ vr, const float* __restrict__ vi, float* __restrict__ xcat){
  int idx = blockIdx.x*256 + threadIdx.x; // L*128
  int i = idx >> 7, c = idx & 127;
  xcat[idx] = (c<64) ? vr[(i<<6)+c] : vi[(i<<6)+c-64];
}

// LDS-tiled transpose: out[n*K+k] = bf16(in[k*N+n]); grid ((N+31)/32,(K+31)/32), 256 threads
__global__ __launch_bounds__(256) void tr_k(const float* __restrict__ in, ushort* __restrict__ out, int K, int N){
  __shared__ float tile[32][33];
  int tx = threadIdx.x & 31, ty = threadIdx.x >> 5;
  int k0 = blockIdx.y*32, n0 = blockIdx.x*32;
  #pragma unroll
  for (int q=0;q<4;++q){
    int k = k0 + ty + q*8, n = n0 + tx;
    if (k < K && n < N) tile[ty+q*8][tx] = in[(size_t)k*N + n];
  }
  __syncthreads();
  #pragma unroll
  for (int q=0;q<4;++q){
    int n = n0 + ty + q*8, k = k0 + tx;
    if (n < N && k < K) out[(size_t)n*K + k] = f2bf(tile[tx][ty+q*8]);
  }
}

// Prologue GEMM (small): C[M,N] = A[M,K] * Bt^T + bias, fp32 A, fp32 out
__global__ __launch_bounds__(256) void gemm0_k(
  const float* __restrict__ A, int lda, const ushort* __restrict__ Bt,
  int N, int K, float* __restrict__ of, const float* __restrict__ bias)
{
  __shared__ __align__(16) ushort As[64*32];
  __shared__ __align__(16) ushort Bs[64*32];
  int tid = threadIdx.x;
  int n0 = blockIdx.x*64, m0 = blockIdx.y*64;
  int w = tid>>6, lane = tid&63;
  int wm = (w>>1)*32, wn = (w&1)*32;
  int sr = tid>>2, skk = (tid&3)*8;
  floatx4 acc[2][2] = {};
  for (int k0=0; k0<K; k0+=32){
    float4 v0 = *(const float4*)(A + (size_t)(m0+sr)*lda + k0 + skk);
    float4 v1 = *(const float4*)(A + (size_t)(m0+sr)*lda + k0 + skk + 4);
    ushort o[8] = {f2bf(v0.x),f2bf(v0.y),f2bf(v0.z),f2bf(v0.w),f2bf(v1.x),f2bf(v1.y),f2bf(v1.z),f2bf(v1.w)};
    *(uint4*)(&As[sr*32+skk]) = *(uint4*)o;
    uint4 bv = make_uint4(0u,0u,0u,0u);
    if (n0+sr < N) bv = *(const uint4*)(Bt + (size_t)(n0+sr)*K + k0 + skk);
    *(uint4*)(&Bs[sr*32+skk]) = bv;
    __syncthreads();
    int kq = lane>>4, l16 = lane&15;
    short8 bf0 = *(const short8*)(&Bs[(wn      + l16)*32 + kq*8]);
    short8 bf1 = *(const short8*)(&Bs[(wn + 16 + l16)*32 + kq*8]);
    #pragma unroll
    for (int ti=0; ti<2; ++ti){
      short8 af = *(const short8*)(&As[(wm + ti*16 + l16)*32 + kq*8]);
      acc[ti][0] = __builtin_amdgcn_mfma_f32_16x16x32_bf16(af, bf0, acc[ti][0], 0,0,0);
      acc[ti][1] = __builtin_amdgcn_mfma_f32_16x16x32_bf16(af, bf1, acc[ti][1], 0,0,0);
    }
    __syncthreads();
  }
  int l16 = lane&15, lq = lane>>4;
  #pragma unroll
  for (int ti=0; ti<2; ++ti)
  #pragma unroll
  for (int tj=0; tj<2; ++tj)
  #pragma unroll
  for (int r=0; r<4; ++r){
    int row = m0 + wm + ti*16 + lq*4 + r;
    int col = n0 + wn + tj*16 + l16;
    if (col >= N) continue;
    of[(size_t)row*N + col] = acc[ti][tj][r] + bias[col];
  }
}

// gemm1: round-8 structure + LDS-staged coalesced output tiles.
// cols 0..639 -> xbc bf16 (pre-conv), 640..647 -> softplus dt (fp32)
__global__ __launch_bounds__(256) void gemm1_k(
  const float* __restrict__ xs,
  const float* __restrict__ lnw, const float* __restrict__ lnb,
  const ushort* __restrict__ Wt,
  ushort* __restrict__ xbc, float* __restrict__ odt, const float* __restrict__ dtb)
{
  __shared__ __align__(16) ushort As[64*264];
  __shared__ __align__(16) ushort Bs[64*32];
  __shared__ __align__(16) ushort Cst[64*64];
  int tid = threadIdx.x;
  int m0 = blockIdx.x*64;
  int w = tid>>6, lane = tid&63;
  int wm = (w>>1)*32, wn = (w&1)*32;
  int sr = tid>>2, skk = (tid&3)*8;
  int l16 = lane&15, kq = lane>>4;
  // stage A-row + fused LN stats (4 threads per row, shuffle-reduce over lane&3)
  {
    float va[8][8];
    float s = 0.f, s2 = 0.f;
    const float* rowp = xs + (size_t)(m0+sr)*256;
    #pragma unroll
    for (int ki=0;ki<8;++ki){
      float4 v0 = *(const float4*)(rowp + ki*32 + skk);
      float4 v1 = *(const float4*)(rowp + ki*32 + skk + 4);
      va[ki][0]=v0.x; va[ki][1]=v0.y; va[ki][2]=v0.z; va[ki][3]=v0.w;
      va[ki][4]=v1.x; va[ki][5]=v1.y; va[ki][6]=v1.z; va[ki][7]=v1.w;
      #pragma unroll
      for (int j=0;j<8;++j){ s += va[ki][j]; s2 += va[ki][j]*va[ki][j]; }
    }
    s  += __shfl_xor(s,1,64);  s  += __shfl_xor(s,2,64);
    s2 += __shfl_xor(s2,1,64); s2 += __shfl_xor(s2,2,64);
    float mu = s*(1.f/256.f);
    float var = s2*(1.f/256.f) - mu*mu;
    float rs = rsqrtf(fmaxf(var,0.f)+1e-5f);
    #pragma unroll
    for (int ki=0;ki<8;++ki){
      ushort o[8];
      #pragma unroll
      for (int j=0;j<8;++j) o[j] = f2bf((va[ki][j]-mu)*rs*lnw[ki*32+skk+j] + lnb[ki*32+skk+j]);
      *(uint4*)(&As[sr*264 + ki*32 + skk]) = *(uint4*)o;
    }
  }
  __syncthreads();
  for (int nt=0; nt<11; ++nt){
    floatx4 acc[2][2] = {};
    for (int k0=0; k0<256; k0+=32){
      int nr = 512 + nt*64 + sr;
      uint4 bv = make_uint4(0u,0u,0u,0u);
      if (nr < 1160) bv = *(const uint4*)(Wt + (size_t)nr*256 + k0 + skk);
      *(uint4*)(&Bs[sr*32+skk]) = bv;
      __syncthreads();
      short8 bf0 = *(const short8*)(&Bs[(wn      + l16)*32 + kq*8]);
      short8 bf1 = *(const short8*)(&Bs[(wn + 16 + l16)*32 + kq*8]);
      #pragma unroll
      for (int ti=0; ti<2; ++ti){
        short8 af = *(const short8*)(&As[(wm + ti*16 + l16)*264 + k0 + kq*8]);
        acc[ti][0] = __builtin_amdgcn_mfma_f32_16x16x32_bf16(af, bf0, acc[ti][0], 0,0,0);
        acc[ti][1] = __builtin_amdgcn_mfma_f32_16x16x32_bf16(af, bf1, acc[ti][1], 0,0,0);
      }
      __syncthreads();
    }
    if (nt < 10){
      // stage tile, then coalesced 128B-row stores
      #pragma unroll
      for (int mt=0; mt<2; ++mt)
      #pragma unroll
      for (int tj=0; tj<2; ++tj)
      #pragma unroll
      for (int r=0; r<4; ++r)
        Cst[(wm + mt*16 + kq*4 + r)*64 + wn + tj*16 + l16] = f2bf(acc[mt][tj][r]);
      __syncthreads();
      int row = tid>>3, cg = (tid&7)*8;
      *(uint4*)(xbc + (size_t)(m0+row)*640 + nt*64 + cg)    = *(uint4*)(&Cst[row*64 + cg]);
      *(uint4*)(xbc + (size_t)(m0+row+32)*640 + nt*64 + cg) = *(uint4*)(&Cst[(row+32)*64 + cg]);
      __syncthreads();
    } else {
      #pragma unroll
      for (int mt=0; mt<2; ++mt)
      #pragma unroll
      for (int tj=0; tj<2; ++tj)
      #pragma unroll
      for (int r=0; r<4; ++r){
        int row = m0 + wm + mt*16 + kq*4 + r;
        int col = nt*64 + wn + tj*16 + l16;
        if (col < 648) odt[(size_t)row*8 + (col-640)] = softplusf(acc[mt][tj][r] + dtb[col-640]);
      }
    }
  }
}

// zgate: round-8 version — LN stats fused; z = LN(xs)@Wz; g = y*silu(z); in-place; rrg
__global__ __launch_bounds__(256) void zgate_k(
  const float* __restrict__ xs,
  const float* __restrict__ lnw, const float* __restrict__ lnb,
  const ushort* __restrict__ Wzt, ushort* __restrict__ xbc,
  const float* __restrict__ rmsw, float* __restrict__ rrg)
{
  __shared__ __align__(16) ushort As[64*264];
  __shared__ __align__(16) ushort Bs[64*32];
  __shared__ float gsum[64*32];
  int tid = threadIdx.x;
  int m0 = blockIdx.x*64;
  int w = tid>>6, lane = tid&63;
  int wm = (w>>1)*32, wn = (w&1)*32;
  int sr = tid>>2, skk = (tid&3)*8;
  int l16 = lane&15, kq = lane>>4;
  float va[8][8];
  float s = 0.f, s2 = 0.f;
  const float* rowp = xs + (size_t)(m0+sr)*256;
  #pragma unroll
  for (int ki=0;ki<8;++ki){
    float4 v0 = *(const float4*)(rowp + ki*32 + skk);
    float4 v1 = *(const float4*)(rowp + ki*32 + skk + 4);
    va[ki][0]=v0.x; va[ki][1]=v0.y; va[ki][2]=v0.z; va[ki][3]=v0.w;
    va[ki][4]=v1.x; va[ki][5]=v1.y; va[ki][6]=v1.z; va[ki][7]=v1.w;
    #pragma unroll
    for (int j=0;j<8;++j){ s += va[ki][j]; s2 += va[ki][j]*va[ki][j]; }
  }
  s  += __shfl_xor(s,1,64);  s  += __shfl_xor(s,2,64);
  s2 += __shfl_xor(s2,1,64); s2 += __shfl_xor(s2,2,64);
  float mu = s*(1.f/256.f);
  float var = s2*(1.f/256.f) - mu*mu;
  float rs = rsqrtf(fmaxf(var,0.f)+1e-5f);
  #pragma unroll
  for (int ki=0;ki<8;++ki){
    ushort o[8];
    #pragma unroll
    for (int j=0;j<8;++j) o[j] = f2bf((va[ki][j]-mu)*rs*lnw[ki*32+skk+j] + lnb[ki*32+skk+j]);
    *(uint4*)(&As[sr*264 + ki*32 + skk]) = *(uint4*)o;
  }
  float racc[2][4] = {};
  __syncthreads();
  for (int nt=0; nt<8; ++nt){
    floatx4 acc[2][2] = {};
    for (int k0=0; k0<256; k0+=32){
      uint4 bv = *(const uint4*)(Wzt + (size_t)(nt*64 + sr)*256 + k0 + skk);
      *(uint4*)(&Bs[sr*32+skk]) = bv;
      __syncthreads();
      short8 bf0 = *(const short8*)(&Bs[(wn      + l16)*32 + kq*8]);
      short8 bf1 = *(const short8*)(&Bs[(wn + 16 + l16)*32 + kq*8]);
      #pragma unroll
      for (int ti=0; ti<2; ++ti){
        short8 af = *(const short8*)(&As[(wm + ti*16 + l16)*264 + k0 + kq*8]);
        acc[ti][0] = __builtin_amdgcn_mfma_f32_16x16x32_bf16(af, bf0, acc[ti][0], 0,0,0);
        acc[ti][1] = __builtin_amdgcn_mfma_f32_16x16x32_bf16(af, bf1, acc[ti][1], 0,0,0);
      }
      __syncthreads();
    }
    #pragma unroll
    for (int ti=0; ti<2; ++ti)
    #pragma unroll
    for (int tj=0; tj<2; ++tj)
    #pragma unroll
    for (int r=0; r<4; ++r){
      int row = m0 + wm + ti*16 + kq*4 + r;
      int col = nt*64 + wn + tj*16 + l16;
      float z = acc[ti][tj][r];
      float y = bf2f(xbc[(size_t)row*640 + col]);
      float g = y * siluf(z);
      racc[ti][r] += g*g;
      xbc[(size_t)row*640 + col] = f2bf(g * rmsw[col]);
    }
  }
  #pragma unroll
  for (int ti=0; ti<2; ++ti)
  #pragma unroll
  for (int r=0; r<4; ++r)
    gsum[(wm + ti*16 + kq*4 + r)*32 + (w&1)*16 + l16] = racc[ti][r];
  __syncthreads();
  if (tid < 64){
    float s0 = 0.f;
    #pragma unroll 8
    for (int cc=0;cc<32;++cc) s0 += gsum[tid*32+cc];
    rrg[m0+tid] = rsqrtf(s0*(1.f/512.f) + 1e-5f);
  }
}

// gemmNS: round-8 version — N=256 (4 n-tiles, persistent acc), K=KC*256 staged in LDS chunks.
// EPI: 2 = of += acc*rrow[row]; 3 = of = gelu(acc + bias)
template<int KC, int EPI>
__global__ __launch_bounds__(256) void gemmNS_k(
  const ushort* __restrict__ A, int lda, const ushort* __restrict__ Bt,
  float* __restrict__ of, const float* __restrict__ bias, const float* __restrict__ rrow)
{
  __shared__ __align__(16) ushort As[64*264];
  __shared__ __align__(16) ushort Bs[64*32];
  const int K = KC*256;
  int tid = threadIdx.x;
  int m0 = blockIdx.x*64;
  int w = tid>>6, lane = tid&63;
  int wm = (w>>1)*32, wn = (w&1)*32;
  int sr = tid>>2, skk = (tid&3)*8;
  int l16 = lane&15, kq = lane>>4;
  floatx4 acc[4][2][2] = {};
  for (int kb=0; kb<KC; ++kb){
    #pragma unroll
    for (int ki=0;ki<8;++ki)
      *(uint4*)(&As[sr*264 + ki*32 + skk]) = *(const uint4*)(A + (size_t)(m0+sr)*lda + kb*256 + ki*32 + skk);
    __syncthreads();
    for (int nt=0; nt<4; ++nt){
      for (int k0=0; k0<256; k0+=32){
        *(uint4*)(&Bs[sr*32+skk]) = *(const uint4*)(Bt + (size_t)(nt*64+sr)*K + kb*256 + k0 + skk);
        __syncthreads();
        short8 bf0 = *(const short8*)(&Bs[(wn      + l16)*32 + kq*8]);
        short8 bf1 = *(const short8*)(&Bs[(wn + 16 + l16)*32 + kq*8]);
        #pragma unroll
        for (int ti=0; ti<2; ++ti){
          short8 af = *(const short8*)(&As[(wm + ti*16 + l16)*264 + k0 + kq*8]);
          acc[nt][ti][0] = __builtin_amdgcn_mfma_f32_16x16x32_bf16(af, bf0, acc[nt][ti][0], 0,0,0);
          acc[nt][ti][1] = __builtin_amdgcn_mfma_f32_16x16x32_bf16(af, bf1, acc[nt][ti][1], 0,0,0);
        }
        __syncthreads();
      }
    }
  }
  #pragma unroll
  for (int nt=0; nt<4; ++nt)
  #pragma unroll
  for (int ti=0; ti<2; ++ti)
  #pragma unroll
  for (int tj=0; tj<2; ++tj)
  #pragma unroll
  for (int r=0; r<4; ++r){
    int row = m0 + wm + ti*16 + kq*4 + r;
    int col = nt*64 + wn + tj*16 + l16;
    float v = acc[nt][ti][tj][r];
    if (EPI==2) of[(size_t)row*256 + col] += v * rrow[row];
    else        of[(size_t)row*256 + col] = geluf(v + bias[col]);
  }
}

__global__ __launch_bounds__(256) void ln_gelu_k(const float* __restrict__ in, float* __restrict__ out,
    const float* __restrict__ w, const float* __restrict__ b){
  __shared__ float red[256];
  int t = threadIdx.x; size_t base = (size_t)blockIdx.x*256;
  float v = in[base+t];
  float mu = blockSum256(v, red) * (1.f/256.f);
  float dv = v - mu;
  float var = blockSum256(dv*dv, red) * (1.f/256.f);
  float rs = rsqrtf(var + 1e-5f);
  out[base+t] = geluf(dv*rs*w[t] + b[t]);
}

__global__ __launch_bounds__(256) void scatter_k(const float* __restrict__ h, const int* __restrict__ perm, float* __restrict__ xs){
  int blk = blockIdx.x;
  int t = threadIdx.x;
  int d = blk >> 14; int r = blk & 16383;
  int src = perm[d*LSEQ + r];
  xs[(size_t)blk*256 + t] = h[(size_t)src*256 + t];
}

// save 3-row raw lookback per chunk before the in-place conv overwrite; grid 6*NC
__global__ __launch_bounds__(256) void bnd_k(const ushort* __restrict__ xbc, ushort* __restrict__ bnd){
  int b = blockIdx.x;
  int d = b / NC, c = b % NC;
  size_t row0 = (size_t)d*LSEQ + (size_t)c*128;
  for (int idx = threadIdx.x; idx < 3*640; idx += 256){
    int j = idx/640;
    ushort v = (c==0) ? (ushort)0 : xbc[(row0 - 3 + j)*640 + (idx - j*640)];
    bnd[(size_t)b*3*640 + idx] = v;
  }
}

// in-place causal depthwise conv + silu over xbc
__global__ __launch_bounds__(256) void conv_k(ushort* __restrict__ xbc, const ushort* __restrict__ bnd,
    const float* __restrict__ convw, const float* __restrict__ convb){
  int b = blockIdx.x;  // d*NC + c
  int d = b / NC, c = b % NC;
  size_t row0 = (size_t)d*LSEQ + (size_t)c*128;
  int tid = threadIdx.x;
  for (int s0 = tid; s0 < 640; s0 += 256){
    float w0=convw[s0*4], w1=convw[s0*4+1], w2=convw[s0*4+2], w3=convw[s0*4+3];
    float cb=convb[s0];
    float h0=0.f,h1=0.f,h2=0.f;
    if (c != 0){
      const ushort* bp = bnd + (size_t)b*3*640;
      h0=bf2f(bp[s0]); h1=bf2f(bp[640+s0]); h2=bf2f(bp[1280+s0]);
    }
    ushort* p = xbc + row0*640 + s0;
    for (int r=0;r<128;++r){
      float cur = bf2f(*p);
      *p = f2bf(siluf(cb + w0*h0 + w1*h1 + w2*h2 + w3*cur));
      h0=h1; h1=h2; h2=cur;
      p += 640;
    }
  }
}

// SSD pass A (conv'd input): dS[p][n] = sum_s exp(Ah*(cs[127]-cs[s]))*dt_s * x_s[p] * B_s[n]
__global__ __launch_bounds__(256) void ssd_dstate_k(
  const ushort* __restrict__ xbc, const float* __restrict__ dtf, const float* __restrict__ alog,
  ushort* __restrict__ dsb, float* __restrict__ gam, int dh0)
{
  int c = blockIdx.x, dhg = blockIdx.y;
  int dh = dh0 + dhg;
  int d = dh >> 3, h = dh & 7;
  int tid = threadIdx.x;
  float Ah = -__expf(alog[h]);
  __shared__ __align__(16) ushort XT[64*136];
  __shared__ __align__(16) ushort BwT[64*136];
  __shared__ float sdt[128];
  __shared__ float scs[128];
  size_t row0 = (size_t)d*LSEQ + (size_t)c*128;
  if (tid < 128){
    float v = dtf[(row0+tid)*8 + h];
    sdt[tid] = v;
    float x = v;
    #pragma unroll
    for (int o=1;o<64;o<<=1){ float t = __shfl_up(x,(unsigned)o,64); if ((tid&63)>=o) x += t; }
    scs[tid] = x;
  }
  __syncthreads();
  if (tid>=64 && tid<128) scs[tid] += scs[63];
  __syncthreads();
  float csLast = scs[127];
  if (tid == 0) gam[(size_t)dh*NC + c] = __expf(Ah*csLast);
  for (int idx = tid; idx < 128*16; idx += 256){
    int s = idx >> 4, g = idx & 15;
    int ch = (g<8) ? h*64 + g*8 : 512 + (g-8)*8;
    uint4 v = *(const uint4*)(xbc + (row0+s)*640 + ch);
    ushort u[8]; *(uint4*)u = v;
    if (g < 8){
      int c0 = g*8;
      #pragma unroll
      for (int j=0;j<8;++j) XT[(c0+j)*136 + s] = u[j];
    } else {
      float wgt = __expf(Ah*(csLast - scs[s])) * sdt[s];
      int n0 = (g-8)*8;
      #pragma unroll
      for (int j=0;j<8;++j) BwT[(n0+j)*136 + s] = f2bf(bf2f(u[j])*wgt);
    }
  }
  __syncthreads();
  int w = tid>>6, lane = tid&63, l16 = lane&15, kq = lane>>4;
  floatx4 acc[4] = {};
  #pragma unroll
  for (int kw=0; kw<4; ++kw){
    short8 bfrag = *(const short8*)(&BwT[(16*w + l16)*136 + kw*32 + kq*8]);
    #pragma unroll
    for (int mt=0; mt<4; ++mt){
      short8 afrag = *(const short8*)(&XT[(mt*16 + l16)*136 + kw*32 + kq*8]);
      acc[mt] = __builtin_amdgcn_mfma_f32_16x16x32_bf16(afrag, bfrag, acc[mt], 0,0,0);
    }
  }
  size_t base = ((size_t)dhg*NC + c)*4096;
  int n = 16*w + l16;
  int kb = n>>5, nm = n&31;
  #pragma unroll
  for (int mt=0; mt<4; ++mt)
  #pragma unroll
  for (int r=0; r<4; ++r){
    int p = mt*16 + kq*4 + r;
    dsb[base + (size_t)kb*2048 + p*32 + nm] = f2bf(acc[mt][r]);
  }
}

// SSD pass B: grid (g, 2); each block scans half the state (2048 elems, 8/thread), 4-deep prefetch
__global__ __launch_bounds__(256) void ssd_scan_k(ushort* __restrict__ dsb, const float* __restrict__ gam, int dh0)
{
  int dhg = blockIdx.x, z = blockIdx.y;
  int tid = threadIdx.x;
  float S[8];
  #pragma unroll
  for (int j=0;j<8;++j) S[j]=0.f;
  ushort* base = dsb + (size_t)dhg*NC*4096 + (size_t)z*2048 + (size_t)(tid>>2)*32 + (size_t)(tid&3)*8;
  const float* g = gam + (size_t)(dh0+dhg)*NC;
  uint4 pf[4];
  #pragma unroll
  for (int j=0;j<4;++j) pf[j] = *(const uint4*)(base + (size_t)j*4096);
  for (int c=0;c<NC;++c){
    ushort cur[8];
    *(uint4*)cur = pf[c&3];
    if (c+4 < NC) pf[c&3] = *(const uint4*)(base + (size_t)(c+4)*4096);
    float gamma = g[c];
    ushort pfo[8];
    #pragma unroll
    for (int j=0;j<8;++j) pfo[j] = f2bf(S[j]);
    *(uint4*)(base + (size_t)c*4096) = *(uint4*)pfo;
    #pragma unroll
    for (int j=0;j<8;++j) S[j] = gamma*S[j] + bf2f(cur[j]);
  }
}

// SSD pass C: Y = a_t*(C @ Sin) + (Lmask o (C@B^T)) @ X + D*x ; y in-place into x-slice.
// C fragments loaded straight from global (read-only cols 576..639) — no Cs LDS tile.
__global__ __launch_bounds__(256) void ssd_out_k(
  ushort* __restrict__ xbc, const ushort* __restrict__ dsb,
  const float* __restrict__ dtf, const float* __restrict__ alog, const float* __restrict__ dskip, int dh0)
{
  int c = blockIdx.x, dhg = blockIdx.y;
  int dh = dh0 + dhg;
  int d = dh>>3, h = dh&7;
  int tid = threadIdx.x;
  float Ah = -__expf(alog[h]);
  float Dv = dskip[h];
  __shared__ __align__(16) ushort Bs2[2][128][32];
  __shared__ __align__(16) ushort XT[64*136];
  __shared__ __align__(16) ushort Pl[4][32*32];
  __shared__ float sdt[128];
  __shared__ float scs[128];
  size_t row0 = (size_t)d*LSEQ + (size_t)c*128;
  if (tid < 128){
    float v = dtf[(row0+tid)*8 + h];
    sdt[tid] = v;
    float x = v;
    #pragma unroll
    for (int o=1;o<64;o<<=1){ float t = __shfl_up(x,(unsigned)o,64); if ((tid&63)>=o) x += t; }
    scs[tid] = x;
  }
  __syncthreads();
  if (tid>=64 && tid<128) scs[tid] += scs[63];
  __syncthreads();
  for (int idx = tid; idx < 128*16; idx += 256){
    int s = idx >> 4, g = idx & 15;
    int ch = (g<8) ? h*64 + g*8 : 512 + (g-8)*8;
    uint4 v = *(const uint4*)(xbc + (row0+s)*640 + ch);
    ushort u[8]; *(uint4*)u = v;
    if (g < 8){
      int c0 = g*8;
      #pragma unroll
      for (int j=0;j<8;++j) XT[(c0+j)*136 + s] = u[j];
    } else {
      int n0 = (g-8)*8;
      #pragma unroll
      for (int j=0;j<8;++j) Bs2[(n0+j)>>5][s][(n0+j)&31] = u[j];
    }
  }
  int w = tid>>6, lane = tid&63, l16 = lane&15, kq = lane>>4;
  size_t pbase = ((size_t)dhg*NC + c)*4096;
  short8 sinf[4][2];
  #pragma unroll
  for (int nt=0; nt<4; ++nt)
  #pragma unroll
  for (int kb=0; kb<2; ++kb)
    sinf[nt][kb] = *(const short8*)(dsb + pbase + (size_t)kb*2048 + (nt*16+l16)*32 + kq*8);
  // C fragments from global: rows w*32+mt*16+l16, cols 576 + kb*32 + kq*8
  short8 cfr[2][2];
  #pragma unroll
  for (int mt=0; mt<2; ++mt)
  #pragma unroll
  for (int kb=0; kb<2; ++kb)
    cfr[mt][kb] = *(const short8*)(xbc + (row0 + w*32 + mt*16 + l16)*640 + 576 + kb*32 + kq*8);
  __syncthreads();
  floatx4 Y[2][4] = {};
  #pragma unroll
  for (int mt=0; mt<2; ++mt)
  #pragma unroll
  for (int nt=0; nt<4; ++nt)
  #pragma unroll
  for (int kb=0; kb<2; ++kb)
    Y[mt][nt] = __builtin_amdgcn_mfma_f32_16x16x32_bf16(cfr[mt][kb], sinf[nt][kb], Y[mt][nt], 0,0,0);
  #pragma unroll
  for (int mt=0; mt<2; ++mt){
    float ar[4];
    #pragma unroll
    for (int r=0;r<4;++r) ar[r] = __expf(Ah*scs[w*32 + mt*16 + kq*4 + r]);
    #pragma unroll
    for (int nt=0; nt<4; ++nt)
    #pragma unroll
    for (int r=0;r<4;++r) Y[mt][nt][r] *= ar[r];
  }
  for (int st=0; st<=w; ++st){
    floatx4 P[2][2] = {};
    #pragma unroll
    for (int nt2=0; nt2<2; ++nt2)
    #pragma unroll
    for (int kb=0; kb<2; ++kb){
      short8 bfr = *(const short8*)(&Bs2[kb][st*32 + nt2*16 + l16][kq*8]);
      #pragma unroll
      for (int mt=0; mt<2; ++mt)
        P[mt][nt2] = __builtin_amdgcn_mfma_f32_16x16x32_bf16(cfr[mt][kb], bfr, P[mt][nt2], 0,0,0);
    }
    #pragma unroll
    for (int mt=0; mt<2; ++mt)
    #pragma unroll
    for (int nt2=0; nt2<2; ++nt2)
    #pragma unroll
    for (int r=0; r<4; ++r){
      int tl = w*32 + mt*16 + kq*4 + r;
      int sl = st*32 + nt2*16 + l16;
      float e = __expf(fminf(Ah*(scs[tl]-scs[sl]), 0.f)) * sdt[sl];
      float v = (sl <= tl) ? P[mt][nt2][r]*e : 0.f;
      Pl[w][(mt*16 + kq*4 + r)*32 + nt2*16 + l16] = f2bf(v);
    }
    #pragma unroll
    for (int mt=0; mt<2; ++mt){
      short8 afr = *(const short8*)(&Pl[w][(mt*16 + l16)*32 + kq*8]);
      #pragma unroll
      for (int nt=0; nt<4; ++nt){
        short8 xfr = *(const short8*)(&XT[(nt*16 + l16)*136 + st*32 + kq*8]);
        Y[mt][nt] = __builtin_amdgcn_mfma_f32_16x16x32_bf16(afr, xfr, Y[mt][nt], 0,0,0);
      }
    }
  }
  #pragma unroll
  for (int mt=0; mt<2; ++mt)
  #pragma unroll
  for (int nt=0; nt<4; ++nt)
  #pragma unroll
  for (int r=0; r<4; ++r){
    int tl = w*32 + mt*16 + kq*4 + r;
    int p  = nt*16 + l16;
    float xv = bf2f(XT[p*136 + tl]);
    float yv = Y[mt][nt][r] + Dv*xv;
    xbc[(row0 + tl)*640 + h*64 + p] = f2bf(yv);
  }
}

// Ultimate fallback: sequential scan with conv fused (raw xbc input)
__global__ __launch_bounds__(512) void scan_legacy_k(ushort* __restrict__ xbc, const float* __restrict__ dtf,
  const float* __restrict__ convw, const float* __restrict__ convb,
  const float* __restrict__ alog, const float* __restrict__ dskip)
{
  int d = blockIdx.x >> 3, h = blockIdx.x & 7;
  int tid = threadIdx.x, p = tid & 63, sg = tid >> 6;
  float Ah = -__expf(alog[h]);
  float Dv = dskip[h];
  __shared__ float raw[19][192];
  __shared__ float cw[192][4];
  __shared__ float cb[192];
  __shared__ float sxc[16][192];
  __shared__ float sdt[16];
  __shared__ float sy[16][8][64];
  for (int c = tid; c < 192; c += 512){
    int ch = (c<64) ? h*64+c : (c<128 ? 512+(c-64) : 576+(c-128));
    #pragma unroll
    for (int k=0;k<4;++k) cw[c][k] = convw[ch*4+k];
    cb[c] = convb[ch];
  }
  for (int idx = tid; idx < 3*192; idx += 512) raw[idx/192][idx%192] = 0.f;
  float st[8];
  #pragma unroll
  for (int j=0;j<8;++j) st[j]=0.f;
  size_t rowbase = (size_t)d*LSEQ;
  __syncthreads();
  for (int t0=0; t0<LSEQ; t0+=16){
    for (int idx = tid; idx < 16*192; idx += 512){
      int tt = idx/192, c = idx%192;
      int ch = (c<64) ? h*64+c : (c<128 ? 512+(c-64) : 576+(c-128));
      raw[3+tt][c] = bf2f(xbc[(rowbase + t0 + tt)*640 + ch]);
    }
    if (tid < 16) sdt[tid] = dtf[(rowbase + t0 + tid)*8 + h];
    __syncthreads();
    for (int idx = tid; idx < 16*192; idx += 512){
      int tt = idx/192, c = idx%192;
      float v = cb[c] + cw[c][0]*raw[tt][c] + cw[c][1]*raw[tt+1][c]
                      + cw[c][2]*raw[tt+2][c] + cw[c][3]*raw[tt+3][c];
      sxc[tt][c] = siluf(v);
    }
    __syncthreads();
    for (int tt=0; tt<16; ++tt){
      float dtv = sdt[tt];
      float dA = __expf(dtv*Ah);
      float xb = dtv * sxc[tt][p];
      float Bl[8], Cl[8];
      #pragma unroll
      for (int q=0;q<2;++q){
        *(floatx4*)&Bl[q*4] = *(const floatx4*)&sxc[tt][64  + sg*8 + q*4];
        *(floatx4*)&Cl[q*4] = *(const floatx4*)&sxc[tt][128 + sg*8 + q*4];
      }
      float part = 0.f;
      #pragma unroll
      for (int j=0;j<8;++j){ st[j] = st[j]*dA + xb*Bl[j]; part += st[j]*Cl[j]; }
      sy[tt][sg][p] = part;
    }
    __syncthreads();
    for (int idx = tid; idx < 16*64; idx += 512){
      int tt = idx>>6, pp = idx&63;
      float yv = sy[tt][0][pp]+sy[tt][1][pp]+sy[tt][2][pp]+sy[tt][3][pp]
               + sy[tt][4][pp]+sy[tt][5][pp]+sy[tt][6][pp]+sy[tt][7][pp] + Dv*sxc[tt][pp];
      xbc[(rowbase + t0 + tt)*640 + h*64 + pp] = f2bf(yv);
    }
    for (int idx = tid; idx < 3*192; idx += 512){
      int r = idx/192, c = idx%192;
      raw[r][c] = raw[16+r][c];
    }
    __syncthreads();
  }
}

// gather 6 dirs via inv, LayerNorm over 1536, write bf16 (GEMM A-operand)
__global__ __launch_bounds__(256) void fuse_ln_k(const float* __restrict__ xs, const int* __restrict__ inv,
    const float* __restrict__ w, const float* __restrict__ b, ushort* __restrict__ out){
  __shared__ float red[256];
  int i = blockIdx.x, t = threadIdx.x;
  float v[6];
  float s = 0.f;
  #pragma unroll
  for (int d=0; d<6; ++d){
    int r = inv[d*LSEQ + i];
    v[d] = xs[((size_t)d*LSEQ + r)*256 + t];
    s += v[d];
  }
  float mu = blockSum256(s, red) * (1.f/1536.f);
  float s2 = 0.f;
  #pragma unroll
  for (int d=0; d<6; ++d){ float dv = v[d]-mu; s2 += dv*dv; }
  float var = blockSum256(s2, red) * (1.f/1536.f);
  float rs = rsqrtf(var + 1e-5f);
  #pragma unroll
  for (int d=0; d<6; ++d){
    int c = d*256 + t;
    out[(size_t)i*1536 + c] = f2bf((v[d]-mu)*rs*w[c] + b[c]);
  }
}

__global__ void zero_k(float* p){ p[threadIdx.x] = 0.f; }

__global__ __launch_bounds__(256) void pool_k(const float* __restrict__ fused, float* __restrict__ pooled){
  int t = threadIdx.x;
  size_t r0 = (size_t)blockIdx.x*256;
  float s = 0.f;
  for (int r=0;r<256;++r) s += fused[(r0+r)*256 + t];
  atomicAdd(&pooled[t], s);
}

__global__ __launch_bounds__(256) void cls_k(const float* __restrict__ pooled,
  const float* __restrict__ lnw, const float* __restrict__ lnb,
  const float* __restrict__ w1, const float* __restrict__ b1,
  const float* __restrict__ w2, const float* __restrict__ b2,
  const float* __restrict__ w3, const float* __restrict__ b3, float* __restrict__ out)
{
  __shared__ float red[256];
  __shared__ float hcn[768]; __shared__ float h1[512]; __shared__ float h2[256];
  int t = threadIdx.x;
  float m = pooled[t] * (1.f/16384.f);
  float mu = blockSum256(m, red) * (1.f/256.f);
  float dv = m - mu;
  float var = blockSum256(dv*dv, red) * (1.f/256.f);
  float rs = rsqrtf(var + 1e-5f);
  #pragma unroll
  for (int rep=0; rep<3; ++rep){
    int c = rep*256 + t;
    hcn[c] = dv*rs*lnw[c] + lnb[c];
  }
  __syncthreads();
  for (int n=t; n<512; n+=256){
    float a = b1[n];
    for (int c=0;c<768;++c) a += hcn[c]*w1[c*512+n];
    h1[n] = geluf(a);
  }
  __syncthreads();
  {
    float a = b2[t];
    for (int c=0;c<512;++c) a += h1[c]*w2[c*256+t];
    h2[t] = geluf(a);
  }
  __syncthreads();
  if (t<11){
    float a = b3[t];
    for (int c=0;c<256;++c) a += h2[c]*w3[c*11+t];
    out[t] = a;
  }
}

extern "C" void kernel_launch(void* const* d_in, const int* in_sizes, int n_in,
                              void* d_out, int out_size, void* d_ws, size_t ws_size,
                              hipStream_t stream)
{
  const float* vec_real = (const float*)d_in[0];
  const float* vec_imag = (const float*)d_in[1];
  const int*   coords   = (const int*)d_in[2];
  const float* inp_w    = (const float*)d_in[3];
  const float* inp_b    = (const float*)d_in[4];
  const float* inp_ln_w = (const float*)d_in[5];
  const float* inp_ln_b = (const float*)d_in[6];
  const float* ln_w     = (const float*)d_in[7];
  const float* ln_b     = (const float*)d_in[8];
  const float* in_proj_w= (const float*)d_in[9];
  const float* conv_w   = (const float*)d_in[10];
  const float* conv_b   = (const float*)d_in[11];
  const float* dt_bias  = (const float*)d_in[12];
  const float* A_log    = (const float*)d_in[13];
  const float* Dskip    = (const float*)d_in[14];
  const float* rms_w    = (const float*)d_in[15];
  const float* out_proj_w=(const float*)d_in[16];
  const float* fus_ln_w = (const float*)d_in[17];
  const float* fus_ln_b = (const float*)d_in[18];
  const float* fus_w    = (const float*)d_in[19];
  const float* fus_b    = (const float*)d_in[20];
  const float* cls_ln_w = (const float*)d_in[21];
  const float* cls_ln_b = (const float*)d_in[22];
  const float* cls_w1   = (const float*)d_in[23];
  const float* cls_b1   = (const float*)d_in[24];
  const float* cls_w2   = (const float*)d_in[25];
  const float* cls_b2   = (const float*)d_in[26];
  const float* cls_w3   = (const float*)d_in[27];
  const float* cls_b3   = (const float*)d_in[28];
  (void)in_sizes; (void)n_in; (void)out_size;

  char* ws = (char*)d_ws;
  size_t off = 0;
  auto alloc = [&](size_t bytes)->char* { char* p = ws + off; off = (off + bytes + 255) & ~(size_t)255; return p; };
  int*    perm  = (int*)alloc((size_t)6*LSEQ*4);
  int*    inv   = (int*)alloc((size_t)6*LSEQ*4);
  float*  xs    = (float*)alloc((size_t)6*LSEQ*256*4);           // fp32 residual stream
  ushort* xbc   = (ushort*)alloc((size_t)6*LSEQ*640*2);          // raw xBC -> conv'd -> y -> gated g
  float*  dtfb  = (float*)alloc((size_t)6*LSEQ*8*4);
  float*  rrg   = (float*)alloc((size_t)6*LSEQ*4);               // also reused as sort rank buffer (int)
  ushort* wtr   = (ushort*)alloc((size_t)1536*256*2);
  float*  pooled= (float*)alloc(256*4);
  size_t base_off = off;
  if (base_off > ws_size) return;  // diagnostic guard

  // gam (48*NC fp32 = 24.6 KB) lives in the dead tail of wtr
  float* gam = (float*)((char*)wtr + 600*1024);
  int* rankb = (int*)rrg;   // sort scratch; rrg only live inside layer loop, sort runs before

  // adaptive SSD group size: largest g with bnd (2.95 MB) + dsb(g) fitting beyond base
  const size_t BND_SZ = (size_t)6*NC*3*640*2;
  size_t dsb_off = base_off + ((BND_SZ + 255) & ~(size_t)255);
  ushort* bndb = (ushort*)(ws + base_off);
  ushort* dsb  = (ushort*)(ws + dsb_off);
  long long avail2 = (long long)ws_size - (long long)dsb_off;
  int gsize = 0;
  const int cands[10] = {48,24,16,12,8,6,4,3,2,1};
  for (int ci=0; ci<10; ++ci){
    if ((long long)((size_t)cands[ci]*NC*4096*2 + 512) <= avail2){ gsize = cands[ci]; break; }
  }

  // prologue/epilogue temps aliased inside xbc (125.8 MB)
  float*  xcat = (float*)((char*)xbc + 0);
  float*  tmpF = (float*)((char*)xbc + (16u<<20));
  float*  hbuf = (float*)((char*)xbc + (48u<<20));
  ushort* multiB = (ushort*)((char*)xbc + 0);          // 48 MB bf16
  float*  fused  = (float*)((char*)xbc + (100u<<20));  // 16 MB

  dim3 b256(256);
  zrank_k<<<dim3(6*LSEQ/256),b256,0,stream>>>(rankb);
  sortp_k<<<dim3(16,6,8),b256,0,stream>>>(coords, rankb);
  sfin_k<<<dim3(6*LSEQ/256),b256,0,stream>>>(rankb, perm, inv);
  concat_k<<<dim3(LSEQ*128/256),b256,0,stream>>>(vec_real, vec_imag, xcat);
  tr_k<<<dim3(8,4),b256,0,stream>>>(inp_w, wtr, 128, 256);
  gemm0_k<<<dim3(4, LSEQ/64),b256,0,stream>>>(xcat, 128, wtr, 256, 128, tmpF, inp_b);
  ln_gelu_k<<<dim3(LSEQ),b256,0,stream>>>(tmpF, hbuf, inp_ln_w, inp_ln_b);
  scatter_k<<<dim3(6*LSEQ),b256,0,stream>>>(hbuf, perm, xs);

  for (int l=0;l<3;++l){
    const float* cwp = conv_w + (size_t)l*640*4;
    const float* cbp = conv_b + (size_t)l*640;
    const float* alp = A_log + l*8;
    const float* dkp = Dskip + l*8;
    tr_k<<<dim3(37,8),b256,0,stream>>>(in_proj_w + (size_t)l*256*1160, wtr, 256, 1160);
    gemm1_k<<<dim3(6*LSEQ/64),b256,0,stream>>>(xs, ln_w + l*256, ln_b + l*256,
        wtr, xbc, dtfb, dt_bias + l*8);
    if (gsize > 0){
      bnd_k<<<dim3(6*NC),b256,0,stream>>>(xbc, bndb);
      conv_k<<<dim3(6*NC),b256,0,stream>>>(xbc, bndb, cwp, cbp);
      for (int dh0=0; dh0<48; dh0+=gsize){
        ssd_dstate_k<<<dim3(NC,gsize),b256,0,stream>>>(xbc, dtfb, alp, dsb, gam, dh0);
        ssd_scan_k<<<dim3(gsize,2),b256,0,stream>>>(dsb, gam, dh0);
        ssd_out_k<<<dim3(NC,gsize),b256,0,stream>>>(xbc, dsb, dtfb, alp, dkp, dh0);
      }
    } else {
      scan_legacy_k<<<dim3(48),dim3(512),0,stream>>>(xbc, dtfb, cwp, cbp, alp, dkp);
    }
    zgate_k<<<dim3(6*LSEQ/64),b256,0,stream>>>(xs, ln_w + l*256, ln_b + l*256,
        wtr, xbc, rms_w + l*512, rrg);
    tr_k<<<dim3(8,16),b256,0,stream>>>(out_proj_w + (size_t)l*512*256, wtr, 512, 256);
    gemmNS_k<2,2><<<dim3(6*LSEQ/64),b256,0,stream>>>(xbc, 640, wtr, xs, nullptr, rrg);
  }

  fuse_ln_k<<<dim3(LSEQ),b256,0,stream>>>(xs, inv, fus_ln_w, fus_ln_b, multiB);
  tr_k<<<dim3(8,48),b256,0,stream>>>(fus_w, wtr, 1536, 256);
  gemmNS_k<6,3><<<dim3(LSEQ/64),b256,0,stream>>>(multiB, 1536, wtr, fused, fus_b, nullptr);
  zero_k<<<dim3(1),b256,0,stream>>>(pooled);
  pool_k<<<dim3(64),b256,0,stream>>>(fused, pooled);
  cls_k<<<dim3(1),b256,0,stream>>>(pooled, cls_ln_w, cls_ln_b, cls_w1, cls_b1, cls_w2, cls_b2, cls_w3, cls_b3, (float*)d_out);
}